// Round 1
// baseline (394.405 us; speedup 1.0000x reference)
//
#include <hip/hip_runtime.h>

#define NQ 16
#define NSTATE 65536
#define BATCH 256
#define NCLS 10

// GF(2) bookkeeping for virtualized CNOTs:
//   stored[x] = psi_true[A^{-1} x];  mask of Rot(w) = col_w(A); role = row_w(A^{-1})
struct Meta {
  unsigned short l1mask[16];  // layer-1 generalized gate XOR masks
  unsigned short l1role[16];  // layer-1 role parity rows
  unsigned short fin[16];     // final A^{-1} rows for Z expvals
};

__device__ __forceinline__ void apply_gate(float2* S, int tid,
    unsigned mloc, unsigned rloc, unsigned pb,
    float2 U00, float2 U01, float2 U10, float2 U11)
{
  unsigned piv  = mloc & (0u - mloc);   // lowest set bit = pair pivot
  unsigned lowm = piv - 1u;
  #pragma unroll
  for (int it = 0; it < 8; ++it) {
    unsigned p  = (unsigned)tid + (unsigned)it * 256u;   // 2048 pairs
    unsigned x0 = ((p & ~lowm) << 1) | (p & lowm);       // pivot bit = 0
    unsigned x1 = x0 ^ mloc;
    float2 va = S[x0];
    float2 vb = S[x1];
    bool sw = ((__popc(rloc & x0) + pb) & 1u) != 0;      // role parity of x0
    float2 a0 = sw ? vb : va;   // |0> component
    float2 a1 = sw ? va : vb;   // |1> component
    float2 n0, n1;
    n0.x = U00.x*a0.x - U00.y*a0.y + U01.x*a1.x - U01.y*a1.y;
    n0.y = U00.x*a0.y + U00.y*a0.x + U01.x*a1.y + U01.y*a1.x;
    n1.x = U10.x*a0.x - U10.y*a0.y + U11.x*a1.x - U11.y*a1.y;
    n1.y = U10.x*a0.y + U10.y*a0.x + U11.x*a1.y + U11.y*a1.x;
    S[x0] = sw ? n1 : n0;
    S[x1] = sw ? n0 : n1;
  }
}

// Rot(phi,theta,omega) = RZ(omega) RY(theta) RZ(phi): 32 gates -> ws
__global__ void prep_gates(const float* __restrict__ qp, float2* __restrict__ gates)
{
  int g = threadIdx.x;
  if (g >= 32) return;
  float phi = qp[g*3+0], th = qp[g*3+1], om = qp[g*3+2];
  float cth = cosf(0.5f*th), sth = sinf(0.5f*th);
  float a = 0.5f*(phi+om), d = 0.5f*(phi-om);
  float ca = cosf(a), sa = sinf(a), cd = cosf(d), sd = sinf(d);
  gates[g*4+0] = make_float2( ca*cth, -sa*cth);  // m00 = e^{-ia} c
  gates[g*4+1] = make_float2(-cd*sth, -sd*sth);  // m01 = -e^{id} s
  gates[g*4+2] = make_float2( cd*sth, -sd*sth);  // m10 = e^{-id} s
  gates[g*4+3] = make_float2( ca*cth,  sa*cth);  // m11 = e^{ia} c
}

// Pass A: local bits 0..11 (contiguous 4096-chunk). Load x, im=0, apply L0 Rots w=4..15.
__global__ __launch_bounds__(256) void passA(const float* __restrict__ x,
    float2* __restrict__ st, const float2* __restrict__ gates)
{
  __shared__ float2 S[4096];
  int batch = blockIdx.x >> 4;
  int chunk = blockIdx.x & 15;
  int tid = threadIdx.x;
  const float4* xs = (const float4*)(x + (size_t)batch*NSTATE + (size_t)chunk*4096);
  float4* S4 = (float4*)S;
  #pragma unroll
  for (int i = 0; i < 4; ++i) {
    float4 v = xs[tid + i*256];
    int k = tid + i*256;
    S4[2*k+0] = make_float4(v.x, 0.f, v.y, 0.f);
    S4[2*k+1] = make_float4(v.z, 0.f, v.w, 0.f);
  }
  __syncthreads();
  for (int w = 4; w < 16; ++w) {
    float2 U00 = gates[w*4+0], U01 = gates[w*4+1], U10 = gates[w*4+2], U11 = gates[w*4+3];
    unsigned m = 1u << (15 - w);          // global bit == local bit (0..11)
    apply_gate(S, tid, m, m, 0u, U00, U01, U10, U11);
    __syncthreads();
  }
  float4* out4 = (float4*)(st + (size_t)batch*NSTATE + (size_t)chunk*4096);
  #pragma unroll
  for (int i = 0; i < 8; ++i) out4[tid + i*256] = S4[tid + i*256];
}

// Pass B: local bits {15..12, 7..0}; fixed bits 11..8 = c. L0 w=0..3 + L1 gates with mask in 0xF0FF.
__global__ __launch_bounds__(256) void passB(float2* __restrict__ st,
    const float2* __restrict__ gates, Meta meta)
{
  __shared__ float2 S[4096];
  int batch = blockIdx.x >> 4;
  unsigned c = blockIdx.x & 15;
  int tid = threadIdx.x;
  float4* base4 = (float4*)(st + (size_t)batch*NSTATE);
  float4* S4 = (float4*)S;
  #pragma unroll
  for (int i = 0; i < 8; ++i) {
    int k = tid + i*256;                  // local float4 idx: hi(4) | lo2(7)
    int hi = k >> 7, lo2 = k & 127;
    S4[k] = base4[(hi << 11) | (c << 7) | lo2];
  }
  __syncthreads();
  // L0 wires 0..3: global bit 15-w -> local bit 11-w
  for (int w = 0; w < 4; ++w) {
    float2 U00 = gates[w*4+0], U01 = gates[w*4+1], U10 = gates[w*4+2], U11 = gates[w*4+3];
    unsigned mloc = 1u << (11 - w);
    apply_gate(S, tid, mloc, mloc, 0u, U00, U01, U10, U11);
    __syncthreads();
  }
  // L1 gates whose masks fit local bits
  for (int w = 0; w < 16; ++w) {
    unsigned m = meta.l1mask[w];
    if (m & ~0xF0FFu) continue;
    unsigned r = meta.l1role[w];
    unsigned mloc = ((m & 0xF000u) >> 4) | (m & 0xFFu);
    unsigned rloc = ((r & 0xF000u) >> 4) | (r & 0xFFu);
    unsigned pb = (unsigned)__popc(r & (c << 8)) & 1u;   // fixed-bit role parity
    float2 U00 = gates[(16+w)*4+0], U01 = gates[(16+w)*4+1],
           U10 = gates[(16+w)*4+2], U11 = gates[(16+w)*4+3];
    apply_gate(S, tid, mloc, rloc, pb, U00, U01, U10, U11);
    __syncthreads();
  }
  #pragma unroll
  for (int i = 0; i < 8; ++i) {
    int k = tid + i*256;
    int hi = k >> 7, lo2 = k & 127;
    base4[(hi << 11) | (c << 7) | lo2] = S4[k];
  }
}

// Pass C: local bits {12..7, 5..0}; fixed {15,14,13}=f3, {6}=f1. Remaining L1 gates + fused expvals.
__global__ __launch_bounds__(256) void passC(const float2* __restrict__ st,
    const float2* __restrict__ gates, Meta meta, float* __restrict__ partials)
{
  __shared__ float2 S[4096];
  __shared__ float R[4][17];
  int batch = blockIdx.x >> 4;
  unsigned cc = blockIdx.x & 15;
  unsigned f3 = cc >> 1, f1 = cc & 1;
  int tid = threadIdx.x;
  const float4* base4 = (const float4*)(st + (size_t)batch*NSTATE);
  float4* S4 = (float4*)S;
  #pragma unroll
  for (int i = 0; i < 8; ++i) {
    int k = tid + i*256;                  // local float4 idx: hi6(6) | lo2(5)
    int hi6 = k >> 5, lo2 = k & 31;
    S4[k] = base4[(f3 << 12) | (hi6 << 6) | (f1 << 5) | lo2];
  }
  __syncthreads();
  unsigned fixedval = (f3 << 13) | (f1 << 6);
  for (int w = 0; w < 16; ++w) {
    unsigned m = meta.l1mask[w];
    if (!(m & ~0xF0FFu)) continue;        // done in pass B
    unsigned r = meta.l1role[w];
    unsigned mloc = ((m & 0x1F80u) >> 1) | (m & 0x3Fu);  // bits 12..7 -> 11..6
    unsigned rloc = ((r & 0x1F80u) >> 1) | (r & 0x3Fu);
    unsigned pb = (unsigned)__popc(r & fixedval) & 1u;
    float2 U00 = gates[(16+w)*4+0], U01 = gates[(16+w)*4+1],
           U10 = gates[(16+w)*4+2], U11 = gates[(16+w)*4+3];
    apply_gate(S, tid, mloc, rloc, pb, U00, U01, U10, U11);
    __syncthreads();
  }
  // fused Z-expval partials: sv[w] = sum p * (-1)^<fin_w, idx>, tot = sum p
  float tot = 0.f;
  float sv[16];
  #pragma unroll
  for (int w = 0; w < 16; ++w) sv[w] = 0.f;
  #pragma unroll 4
  for (int it = 0; it < 16; ++it) {
    int L = tid + it*256;
    unsigned hi6 = (unsigned)L >> 6, lo6 = (unsigned)L & 63u;
    unsigned idx = (f3 << 13) | (hi6 << 7) | (f1 << 6) | lo6;
    float2 a = S[L];
    float pr = a.x*a.x + a.y*a.y;
    tot += pr;
    #pragma unroll
    for (int w = 0; w < 16; ++w) {
      bool neg = (__popc((unsigned)meta.fin[w] & idx) & 1) != 0;
      sv[w] += neg ? -pr : pr;
    }
  }
  #pragma unroll
  for (int off = 32; off > 0; off >>= 1) {
    tot += __shfl_down(tot, off);
    #pragma unroll
    for (int w = 0; w < 16; ++w) sv[w] += __shfl_down(sv[w], off);
  }
  int wave = tid >> 6, lane = tid & 63;
  if (lane == 0) {
    #pragma unroll
    for (int w = 0; w < 16; ++w) R[wave][w] = sv[w];
    R[wave][16] = tot;
  }
  __syncthreads();
  if (tid < 17) {
    float s = R[0][tid] + R[1][tid] + R[2][tid] + R[3][tid];
    partials[(size_t)blockIdx.x * 17 + tid] = s;
  }
}

// Head: reduce 16 chunk-partials per batch, ev = sv/tot, out = ev @ W^T + b
__global__ __launch_bounds__(64) void head(const float* __restrict__ partials,
    const float* __restrict__ W, const float* __restrict__ bias, float* __restrict__ out)
{
  int b = blockIdx.x, tid = threadIdx.x;
  __shared__ float red[17];
  __shared__ float ev[16];
  if (tid < 17) {
    float s = 0.f;
    for (int c = 0; c < 16; ++c) s += partials[((size_t)b*16 + c)*17 + tid];
    red[tid] = s;
  }
  __syncthreads();
  if (tid < 16) ev[tid] = red[tid] / red[16];
  __syncthreads();
  if (tid < NCLS) {
    float o = bias[tid];
    #pragma unroll
    for (int w = 0; w < 16; ++w) o += ev[w] * W[tid*16 + w];
    out[b*NCLS + tid] = o;
  }
}

extern "C" void kernel_launch(void* const* d_in, const int* in_sizes, int n_in,
                              void* d_out, int out_size, void* d_ws, size_t ws_size,
                              hipStream_t stream) {
  const float* x  = (const float*)d_in[0];   // (256, 65536)
  const float* qp = (const float*)d_in[1];   // (2,16,3)
  const float* W  = (const float*)d_in[2];   // (10,16)
  const float* bv = (const float*)d_in[3];   // (10,)
  float* out = (float*)d_out;                // (256,10) fp32

  // ws layout: state (128 MB) | gates (1 KB) | partials (4096*17 floats)
  float2* st       = (float2*)d_ws;
  float2* gates    = (float2*)((char*)d_ws + (size_t)BATCH * NSTATE * sizeof(float2));
  float*  partials = (float*)((char*)gates + 128 * sizeof(float2));

  // Host GF(2) bookkeeping: virtualize all CNOTs.
  // col[w] = A e_w (update on CNOT(c,t): col_c ^= col_t)
  // inv[w] = row_w(A^{-1}) (update: row_t ^= row_c)
  Meta meta;
  unsigned short col[16], inv[16];
  for (int w = 0; w < 16; ++w) { col[w] = (unsigned short)(1u << (15-w)); inv[w] = col[w]; }
  for (int w = 0; w < 16; ++w) {            // layer-0 CNOT ring, r=1, in order
    int c = w, t = (w + 1) & 15;
    col[c] ^= col[t]; inv[t] ^= inv[c];
  }
  for (int w = 0; w < 16; ++w) { meta.l1mask[w] = col[w]; meta.l1role[w] = inv[w]; }
  for (int w = 0; w < 16; ++w) {            // layer-1 CNOT ring, r=2, in order
    int c = w, t = (w + 2) & 15;
    col[c] ^= col[t]; inv[t] ^= inv[c];
  }
  for (int w = 0; w < 16; ++w) meta.fin[w] = inv[w];

  prep_gates<<<dim3(1), dim3(64), 0, stream>>>(qp, gates);
  passA<<<dim3(BATCH*16), dim3(256), 0, stream>>>(x, st, gates);
  passB<<<dim3(BATCH*16), dim3(256), 0, stream>>>(st, gates, meta);
  passC<<<dim3(BATCH*16), dim3(256), 0, stream>>>(st, gates, meta, partials);
  head<<<dim3(BATCH), dim3(64), 0, stream>>>(partials, W, bv, out);
}

// Round 2
// 197.820 us; speedup vs baseline: 1.9938x; 1.9938x over previous
//
#include <hip/hip_runtime.h>

// ============================================================================
// QuantumHeadAmplitude: 256 x 16-qubit statevector sim, 2 StronglyEntangling
// layers, Z-expvals, linear head.
//
// Algebra (validated R1, absmax 0.0): CNOTs are GF(2)-linear index maps,
// virtualized. stored[x] = psi_true[A^{-1} x]. A layer-1 Rot on wire w becomes
// a generalized 1q gate with XOR mask col_w(A) and role row row_w(A^{-1}).
// Expvals use final A^{-1} rows as parity masks. Normalization deferred
// (unitaries preserve norm): ev = sv/tot.
//
// R2 structure: 3 passes, each = load -> register-resident gate stages
// (32 amps/thread = 5 reg bits, gates fully in VGPRs, compile-time masks)
// -> LDS bit-exchange transposes (fp16-packed, XOR-hash banks) -> store.
// Inter-pass state fp16 (half2 per amp) to halve HBM.
// ============================================================================

#define BATCH 256
#define NCLS 10

typedef float v2f __attribute__((ext_vector_type(2)));
typedef _Float16 f16x2 __attribute__((ext_vector_type(2)));

struct CircuitMeta { unsigned l1mask[16]; unsigned l1role[16]; unsigned fin[16]; };

__host__ __device__ constexpr CircuitMeta make_meta() {
  CircuitMeta m{};
  unsigned col[16], inv[16];
  for (int w = 0; w < 16; ++w) { col[w] = 1u << (15 - w); inv[w] = 1u << (15 - w); }
  for (int w = 0; w < 16; ++w) { int c = w, t = (w + 1) & 15; col[c] ^= col[t]; inv[t] ^= inv[c]; }
  for (int w = 0; w < 16; ++w) { m.l1mask[w] = col[w]; m.l1role[w] = inv[w]; }
  for (int w = 0; w < 16; ++w) { int c = w, t = (w + 2) & 15; col[c] ^= col[t]; inv[t] ^= inv[c]; }
  for (int w = 0; w < 16; ++w) m.fin[w] = inv[w];
  return m;
}
constexpr CircuitMeta META = make_meta();

// XOR-hash for LDS bank spread (GF2-linear: HASH(a^b)=HASH(a)^HASH(b))
__host__ __device__ constexpr unsigned HASH(unsigned i) {
  return i ^ ((i >> 4) & 15u) ^ ((i >> 8) & 15u);
}

__device__ __forceinline__ v2f swp(v2f a) { return __builtin_shufflevector(a, a, 1, 0); }

__device__ __forceinline__ unsigned PK(v2f a) {
  return __builtin_bit_cast(unsigned, __builtin_amdgcn_cvt_pkrtz(a.x, a.y));
}
__device__ __forceinline__ v2f UNPK(unsigned u) {
  f16x2 h = __builtin_bit_cast(f16x2, u);
  return (v2f){(float)h.x, (float)h.y};
}

template<int B0,int B1,int B2,int B3,int B4>
__host__ __device__ constexpr unsigned regval5(int j) {
  return ((unsigned)(j & 1) << B0) | ((unsigned)((j >> 1) & 1) << B1) |
         ((unsigned)((j >> 2) & 1) << B2) | ((unsigned)((j >> 3) & 1) << B3) |
         ((unsigned)((j >> 4) & 1) << B4);
}

// Generalized 1q gate, fully register-resident. Reg bits B0..B4 (global bit
// positions for j bits 0..4). MG = XOR mask (must be covered by reg bits),
// RG = role row (any bits). tp = thread's non-reg index bits (global space,
// incl. block-fixed bits). Role parity = parity(RG&tp) [runtime, hoisted to a
// per-gate U-vs-XUX select] ^ parity(RG&regval(j)) [compile-time renaming].
template<int B0,int B1,int B2,int B3,int B4, unsigned MG, unsigned RG>
__device__ __forceinline__ void gate5(v2f (&A)[32], const float* __restrict__ g,
                                      int gi, unsigned tp) {
  constexpr unsigned cover = (1u<<B0)|(1u<<B1)|(1u<<B2)|(1u<<B3)|(1u<<B4);
  static_assert((MG & ~cover) == 0u, "gate mask not covered by stage reg bits");
  constexpr unsigned mr = ((MG>>B0)&1u) | (((MG>>B1)&1u)<<1) | (((MG>>B2)&1u)<<2)
                        | (((MG>>B3)&1u)<<3) | (((MG>>B4)&1u)<<4);
  static_assert(mr != 0u, "empty reg mask");
  constexpr unsigned pivot = mr & (0u - mr);

  float u00r = g[gi*8+0], u00i = g[gi*8+1], u01r = g[gi*8+2], u01i = g[gi*8+3];
  float u10r = g[gi*8+4], u10i = g[gi*8+5], u11r = g[gi*8+6], u11i = g[gi*8+7];
  const bool s = (__popc(RG & tp) & 1) != 0;   // thread-part role parity
  // E = s ? X*U*X : U  (element swap 00<->11, 01<->10)
  float e00r = s ? u11r : u00r, e00i = s ? u11i : u00i;
  float e01r = s ? u10r : u01r, e01i = s ? u10i : u01i;
  float e10r = s ? u01r : u10r, e10i = s ? u01i : u10i;
  float e11r = s ? u00r : u11r, e11i = s ? u00i : u11i;
  // packed complex-madd forms: acc += {Er,Er}*v + {-Ei,Ei}*swap(v)
  v2f a00 = {e00r, e00r}, b00 = {-e00i, e00i};
  v2f a01 = {e01r, e01r}, b01 = {-e01i, e01i};
  v2f a10 = {e10r, e10r}, b10 = {-e10i, e10i};
  v2f a11 = {e11r, e11r}, b11 = {-e11i, e11i};

  #pragma unroll
  for (int j0 = 0; j0 < 32; ++j0) {
    if (j0 & (int)pivot) continue;           // canonical pair rep (folds)
    const int j1 = j0 ^ (int)mr;
    const bool podd =
      (__builtin_popcount(RG & regval5<B0,B1,B2,B3,B4>(j0)) & 1) != 0; // folds
    v2f v0 = A[j0], v1 = A[j1];
    v2f v0s = swp(v0), v1s = swp(v1);
    if (!podd) {
      A[j0] = a00*v0 + b00*v0s + a01*v1 + b01*v1s;
      A[j1] = a10*v0 + b10*v0s + a11*v1 + b11*v1s;
    } else {
      A[j0] = a11*v0 + b11*v0s + a10*v1 + b10*v1s;
      A[j1] = a01*v0 + b01*v0s + a00*v1 + b00*v1s;
    }
  }
}

// Rot(phi,theta,omega) = RZ(omega) RY(theta) RZ(phi) -> 32 gates x 8 floats
__global__ void prep_gates(const float* __restrict__ qp, float* __restrict__ g) {
  int i = threadIdx.x;
  if (i >= 32) return;
  float phi = qp[i*3+0], th = qp[i*3+1], om = qp[i*3+2];
  float cth = cosf(0.5f*th), sth = sinf(0.5f*th);
  float a = 0.5f*(phi+om), d = 0.5f*(phi-om);
  float ca = cosf(a), sa = sinf(a), cd = cosf(d), sd = sinf(d);
  g[i*8+0] =  ca*cth; g[i*8+1] = -sa*cth;   // m00 = e^{-ia} c
  g[i*8+2] = -cd*sth; g[i*8+3] = -sd*sth;   // m01 = -e^{id} s
  g[i*8+4] =  cd*sth; g[i*8+5] = -sd*sth;   // m10 = e^{-id} s
  g[i*8+6] =  ca*cth; g[i*8+7] =  sa*cth;   // m11 = e^{ia} c
}

// ---------------------------------------------------------------------------
// PASS A: fixed global bits {15,14,13}=f, local {12..0} (packed == global).
// L0 wires 3..15 (single-bit masks, bits 12..0). Stages:
//  S1 reg {8,9,10,11,12} (load layout), S2 reg {3,4,5,6,7}, S3 reg {0,1,2,11,12}.
// ---------------------------------------------------------------------------
__global__ __launch_bounds__(256, 4) void passA(const float* __restrict__ x,
    unsigned* __restrict__ st, const float* __restrict__ g) {
  __shared__ unsigned L[8192];             // fp16-packed exchange buffer, 32 KB
  const int t = threadIdx.x;
  const int batch = blockIdx.x >> 3;
  const unsigned f = blockIdx.x & 7;
  const float* xb = x + ((size_t)batch << 16) + ((size_t)f << 13);

  v2f A[32];
  #pragma unroll
  for (int j = 0; j < 32; ++j) A[j] = (v2f){xb[((unsigned)j << 8) | (unsigned)t], 0.f};

  // S1: wires 3..7 (bits 12..8); roles in reg bits -> tp=0
  gate5<8,9,10,11,12, 0x1000u,0x1000u>(A, g, 3, 0u);
  gate5<8,9,10,11,12, 0x0800u,0x0800u>(A, g, 4, 0u);
  gate5<8,9,10,11,12, 0x0400u,0x0400u>(A, g, 5, 0u);
  gate5<8,9,10,11,12, 0x0200u,0x0200u>(A, g, 6, 0u);
  gate5<8,9,10,11,12, 0x0100u,0x0100u>(A, g, 7, 0u);

  // Exchange S1 -> S2: write base=t rv=j<<8; read base=((t&0xF8)<<5)|(t&7) rv=j<<3
  {
    const unsigned wb = HASH((unsigned)t);
    #pragma unroll
    for (int j = 0; j < 32; ++j) L[wb ^ HASH((unsigned)j << 8)] = PK(A[j]);
    __syncthreads();
    const unsigned rb = HASH((((unsigned)t & 0xF8u) << 5) | ((unsigned)t & 7u));
    #pragma unroll
    for (int j = 0; j < 32; ++j) A[j] = UNPK(L[rb ^ HASH((unsigned)j << 3)]);
  }

  // S2: wires 8..12 (bits 7..3)
  gate5<3,4,5,6,7, 0x0080u,0x0080u>(A, g,  8, 0u);
  gate5<3,4,5,6,7, 0x0040u,0x0040u>(A, g,  9, 0u);
  gate5<3,4,5,6,7, 0x0020u,0x0020u>(A, g, 10, 0u);
  gate5<3,4,5,6,7, 0x0010u,0x0010u>(A, g, 11, 0u);
  gate5<3,4,5,6,7, 0x0008u,0x0008u>(A, g, 12, 0u);

  // Exchange S2 -> S3: read base=t<<3, rv=(j&7)|((j&24)<<8)
  __syncthreads();
  {
    const unsigned wb = HASH((((unsigned)t & 0xF8u) << 5) | ((unsigned)t & 7u));
    #pragma unroll
    for (int j = 0; j < 32; ++j) L[wb ^ HASH((unsigned)j << 3)] = PK(A[j]);
    __syncthreads();
    const unsigned rb = HASH((unsigned)t << 3);
    #pragma unroll
    for (int j = 0; j < 32; ++j)
      A[j] = UNPK(L[rb ^ HASH(((unsigned)j & 7u) | (((unsigned)j & 24u) << 8))]);
  }

  // S3: wires 13,14,15 (bits 2,1,0)
  gate5<0,1,2,11,12, 0x0004u,0x0004u>(A, g, 13, 0u);
  gate5<0,1,2,11,12, 0x0002u,0x0002u>(A, g, 14, 0u);
  gate5<0,1,2,11,12, 0x0001u,0x0001u>(A, g, 15, 0u);

  // Store fp16: amp j=jh*8+k at idx (f<<13)|(jh<<11)|(t<<3)|k -> 2 dwordx4/group
  unsigned* outb = st + ((size_t)batch << 16) + ((size_t)f << 13);
  #pragma unroll
  for (int jh = 0; jh < 4; ++jh) {
    uint4 q0, q1;
    q0.x = PK(A[jh*8+0]); q0.y = PK(A[jh*8+1]); q0.z = PK(A[jh*8+2]); q0.w = PK(A[jh*8+3]);
    q1.x = PK(A[jh*8+4]); q1.y = PK(A[jh*8+5]); q1.z = PK(A[jh*8+6]); q1.w = PK(A[jh*8+7]);
    const unsigned si = ((unsigned)jh << 11) | ((unsigned)t << 3);
    *(uint4*)(outb + si) = q0;
    *(uint4*)(outb + si + 4) = q1;
  }
}

// ---------------------------------------------------------------------------
// PASS B: fixed global bits {9,8,7}=c, local {15..10, 6..0} (packed: g>=10
// shift down 3). L0 wires 0,1,2 then L1 w={0..4, 9..15}. Stages:
//  SB1 reg g{11,12,13,14,15}, SB2 reg g{0,5,6,10,11},
//  SB3 reg g{1,2,3,4,5},      SB4 reg g{0,1,13,14,15}.
// ---------------------------------------------------------------------------
__global__ __launch_bounds__(256, 4) void passB(unsigned* __restrict__ st,
    const float* __restrict__ g) {
  __shared__ unsigned L[8192];
  const int t = threadIdx.x;
  const int batch = blockIdx.x >> 3;
  const unsigned c = blockIdx.x & 7;
  unsigned* stb = st + ((size_t)batch << 16);

  // SB1 load: gidx=(j<<11)|lbase; lbase: t[6:0]->g6..0, t7->g10, c->g9..7
  const unsigned lbase = ((unsigned)t & 127u) | (((unsigned)t & 128u) << 3) | (c << 7);
  v2f A[32];
  #pragma unroll
  for (int j = 0; j < 32; ++j) A[j] = UNPK(stb[((unsigned)j << 11) | lbase]);

  const unsigned tp1 = lbase;  // same bits in global space
  gate5<11,12,13,14,15, 0x8000u,0x8000u>(A, g, 0, tp1);
  gate5<11,12,13,14,15, 0x4000u,0x4000u>(A, g, 1, tp1);
  gate5<11,12,13,14,15, 0x2000u,0x2000u>(A, g, 2, tp1);
  gate5<11,12,13,14,15, META.l1mask[0], META.l1role[0]>(A, g, 16, tp1);
  gate5<11,12,13,14,15, META.l1mask[1], META.l1role[1]>(A, g, 17, tp1);
  gate5<11,12,13,14,15, META.l1mask[2], META.l1role[2]>(A, g, 18, tp1);
  gate5<11,12,13,14,15, META.l1mask[3], META.l1role[3]>(A, g, 19, tp1);

  // Exchange SB1 -> SB2 (packed space): wb=t rv=j<<8;
  // rb=((t&0xF0)<<5)|((t&15)<<1), rv=(j&1)|((j&30)<<4)
  {
    const unsigned wb = HASH((unsigned)t);
    #pragma unroll
    for (int j = 0; j < 32; ++j) L[wb ^ HASH((unsigned)j << 8)] = PK(A[j]);
    __syncthreads();
    const unsigned rb = HASH((((unsigned)t & 0xF0u) << 5) | (((unsigned)t & 15u) << 1));
    #pragma unroll
    for (int j = 0; j < 32; ++j)
      A[j] = UNPK(L[rb ^ HASH(((unsigned)j & 1u) | (((unsigned)j & 30u) << 4))]);
  }

  // SB2: tp: t7..t4->g15..12, t3..t0->g4..1
  const unsigned tp2 = (((unsigned)t & 0xF0u) << 8) | (((unsigned)t & 15u) << 1) | (c << 7);
  gate5<0,5,6,10,11, META.l1mask[4], META.l1role[4]>(A, g, 20, tp2);
  gate5<0,5,6,10,11, META.l1mask[9], META.l1role[9]>(A, g, 25, tp2);

  // Exchange SB2 -> SB3: rb=((t&0xFE)<<5)|(t&1), rv=j<<1
  __syncthreads();
  {
    const unsigned wb = HASH((((unsigned)t & 0xF0u) << 5) | (((unsigned)t & 15u) << 1));
    #pragma unroll
    for (int j = 0; j < 32; ++j)
      L[wb ^ HASH(((unsigned)j & 1u) | (((unsigned)j & 30u) << 4))] = PK(A[j]);
    __syncthreads();
    const unsigned rb = HASH((((unsigned)t & 0xFEu) << 5) | ((unsigned)t & 1u));
    #pragma unroll
    for (int j = 0; j < 32; ++j) A[j] = UNPK(L[rb ^ HASH((unsigned)j << 1)]);
  }

  // SB3: tp: t7..t2->g15..g10, t1->g6, t0->g0
  const unsigned tp3 = (((unsigned)t & 0xFCu) << 8) | (((unsigned)t & 2u) << 5)
                     | ((unsigned)t & 1u) | (c << 7);
  gate5<1,2,3,4,5, META.l1mask[10], META.l1role[10]>(A, g, 26, tp3);
  gate5<1,2,3,4,5, META.l1mask[11], META.l1role[11]>(A, g, 27, tp3);
  gate5<1,2,3,4,5, META.l1mask[12], META.l1role[12]>(A, g, 28, tp3);
  gate5<1,2,3,4,5, META.l1mask[13], META.l1role[13]>(A, g, 29, tp3);

  // Exchange SB3 -> SB4: rb=t<<2, rv=(j&3)|((j&28)<<8) (packed bits {0,1,10,11,12})
  __syncthreads();
  {
    const unsigned wb = HASH((((unsigned)t & 0xFEu) << 5) | ((unsigned)t & 1u));
    #pragma unroll
    for (int j = 0; j < 32; ++j) L[wb ^ HASH((unsigned)j << 1)] = PK(A[j]);
    __syncthreads();
    const unsigned rb = HASH((unsigned)t << 2);
    #pragma unroll
    for (int j = 0; j < 32; ++j)
      A[j] = UNPK(L[rb ^ HASH(((unsigned)j & 3u) | (((unsigned)j & 28u) << 8))]);
  }

  // SB4: tp: t7..t5->g12..g10, t4..t0->g6..g2
  const unsigned tp4 = (((unsigned)t & 0xE0u) << 5) | (((unsigned)t & 31u) << 2) | (c << 7);
  gate5<0,1,13,14,15, META.l1mask[14], META.l1role[14]>(A, g, 30, tp4);
  gate5<0,1,13,14,15, META.l1mask[15], META.l1role[15]>(A, g, 31, tp4);

  // Store: amp j=jh*4+k at gidx = tp4 | (jh<<13) | k -> dwordx4
  #pragma unroll
  for (int jh = 0; jh < 8; ++jh) {
    uint4 q;
    q.x = PK(A[jh*4+0]); q.y = PK(A[jh*4+1]); q.z = PK(A[jh*4+2]); q.w = PK(A[jh*4+3]);
    *(uint4*)(stb + (tp4 | ((unsigned)jh << 13))) = q;
  }
}

// ---------------------------------------------------------------------------
// PASS C: fixed {15,14,13}=f, local {12..0}. Reg {6,7,8,9,10}: L1 w=5,6,7,8.
// Then fused Z-expvals with compile-time reg signs + hoisted thread signs.
// ---------------------------------------------------------------------------
__global__ __launch_bounds__(256, 4) void passC(const unsigned* __restrict__ st,
    const float* __restrict__ g, float* __restrict__ partials) {
  __shared__ float R[4][17];
  const int t = threadIdx.x;
  const int batch = blockIdx.x >> 3;
  const unsigned f = blockIdx.x & 7;
  const unsigned* stb = st + ((size_t)batch << 16);

  // cbase: f->g15..13, t7,t6->g12,g11, t5..t0->g5..0 ; j->g10..6
  const unsigned cbase = (f << 13) | (((unsigned)t & 192u) << 5) | ((unsigned)t & 63u);
  v2f A[32];
  #pragma unroll
  for (int j = 0; j < 32; ++j) A[j] = UNPK(stb[cbase | ((unsigned)j << 6)]);

  gate5<6,7,8,9,10, META.l1mask[5], META.l1role[5]>(A, g, 21, cbase);
  gate5<6,7,8,9,10, META.l1mask[6], META.l1role[6]>(A, g, 22, cbase);
  gate5<6,7,8,9,10, META.l1mask[7], META.l1role[7]>(A, g, 23, cbase);
  gate5<6,7,8,9,10, META.l1mask[8], META.l1role[8]>(A, g, 24, cbase);

  float sv[16], tot = 0.f;
  #pragma unroll
  for (int w = 0; w < 16; ++w) sv[w] = 0.f;
  #pragma unroll
  for (int j = 0; j < 32; ++j) {
    const float pr = A[j].x*A[j].x + A[j].y*A[j].y;
    tot += pr;
    #pragma unroll
    for (int w = 0; w < 16; ++w) {
      const bool neg = (__builtin_popcount(META.fin[w] & ((unsigned)j << 6)) & 1) != 0; // folds
      sv[w] += neg ? -pr : pr;
    }
  }
  #pragma unroll
  for (int w = 0; w < 16; ++w)
    if (__popc(META.fin[w] & cbase) & 1) sv[w] = -sv[w];   // thread-part sign

  #pragma unroll
  for (int off = 32; off; off >>= 1) {
    tot += __shfl_xor(tot, off, 64);
    #pragma unroll
    for (int w = 0; w < 16; ++w) sv[w] += __shfl_xor(sv[w], off, 64);
  }
  const int wave = t >> 6, lane = t & 63;
  if (lane == 0) {
    #pragma unroll
    for (int w = 0; w < 16; ++w) R[wave][w] = sv[w];
    R[wave][16] = tot;
  }
  __syncthreads();
  if (t < 17) {
    const float s2 = R[0][t] + R[1][t] + R[2][t] + R[3][t];
    partials[(size_t)blockIdx.x * 17 + t] = s2;
  }
}

__global__ __launch_bounds__(64) void head(const float* __restrict__ partials,
    const float* __restrict__ W, const float* __restrict__ bias,
    float* __restrict__ out) {
  const int b = blockIdx.x, tid = threadIdx.x;
  __shared__ float red[17];
  __shared__ float ev[16];
  if (tid < 17) {
    float s = 0.f;
    #pragma unroll
    for (int ch = 0; ch < 8; ++ch) s += partials[(size_t)((b << 3) + ch) * 17 + tid];
    red[tid] = s;
  }
  __syncthreads();
  if (tid < 16) ev[tid] = red[tid] / red[16];
  __syncthreads();
  if (tid < NCLS) {
    float o = bias[tid];
    #pragma unroll
    for (int w = 0; w < 16; ++w) o += ev[w] * W[tid*16 + w];
    out[b*NCLS + tid] = o;
  }
}

extern "C" void kernel_launch(void* const* d_in, const int* in_sizes, int n_in,
                              void* d_out, int out_size, void* d_ws, size_t ws_size,
                              hipStream_t stream) {
  const float* x  = (const float*)d_in[0];   // (256, 65536)
  const float* qp = (const float*)d_in[1];   // (2,16,3)
  const float* W  = (const float*)d_in[2];   // (10,16)
  const float* bv = (const float*)d_in[3];   // (10,)
  float* out = (float*)d_out;                // (256,10) fp32

  // ws: fp16 state (64 MB) | gates (1 KB) | partials (2048*17 floats)
  unsigned* st     = (unsigned*)d_ws;
  float*    gates  = (float*)((char*)d_ws + (size_t)BATCH * 65536 * 4);
  float*    parts  = (float*)((char*)gates + 1024);

  prep_gates<<<dim3(1), dim3(64), 0, stream>>>(qp, gates);
  passA<<<dim3(BATCH*8), dim3(256), 0, stream>>>(x, st, gates);
  passB<<<dim3(BATCH*8), dim3(256), 0, stream>>>(st, gates);
  passC<<<dim3(BATCH*8), dim3(256), 0, stream>>>(st, gates, parts);
  head<<<dim3(BATCH), dim3(64), 0, stream>>>(parts, W, bv, out);
}